// Round 14
// baseline (227.860 us; speedup 1.0000x reference)
//
#include <hip/hip_runtime.h>
#include <cmath>

// Problem constants
#define NROWS 800        // BS*NQ
#define NCLS  81
#define MT    160        // targets
#define PPX   65536      // pixels per mask
#define SSPLIT 64        // K splits
#define CHUNK 1024       // PPX / SSPLIT
#define BK    64         // K per iteration
#define ITERS (CHUNK / BK)   // 16
#define WROWS 16         // rows per wave
#define RB    50         // 800/16

// Workspace layout (bytes)
#define OFF_TBF   0
#define SZ_TBF    (MT * PPX * 2)                 // 20,971,520 (bf16, natural layout)
#define OFF_CROSS (SZ_TBF)
#define OFF_SDOT  (OFF_CROSS + NROWS * MT * 4)
#define OFF_ROW   (OFF_SDOT + NROWS * MT * 4)
#define OFF_SSUM  (OFF_ROW + NROWS * 4)
#define OFF_TSUM  (OFF_SSUM + NROWS * 4)
#define OFF_PROB  (OFF_TSUM + MT * 4)
#define OFF_END   (OFF_PROB + NROWS * NCLS * 4)

typedef __attribute__((ext_vector_type(8))) short bf16x8;
typedef __attribute__((ext_vector_type(4))) float f32x4;

__device__ __forceinline__ unsigned short f2bf(float f) {
    unsigned int u = __float_as_uint(f);
    unsigned int r = (u + 0x7FFFu + ((u >> 16) & 1u)) >> 16;   // RNE
    return (unsigned short)r;
}

// ---------------------------------------------------------------------------
// Kernel 1: tgt_mask fp32 -> bf16 (natural row-major) + exact tsum[m].
// ---------------------------------------------------------------------------
__global__ __launch_bounds__(256) void prep_kernel(const float* __restrict__ tgt_mask,
                                                   char* __restrict__ ws) {
    int g = blockIdx.x * 256 + threadIdx.x;
    int m = g >> 13;            // 8192 8-px chunks per row
    int kc = g & 8191;
    const float4* src = (const float4*)(tgt_mask + (size_t)m * PPX + (kc << 3));
    float4 a = src[0], b = src[1];
    float part = a.x + a.y + a.z + a.w + b.x + b.y + b.z + b.w;

    uint4 o;
    o.x = (unsigned)f2bf(a.x) | ((unsigned)f2bf(a.y) << 16);
    o.y = (unsigned)f2bf(a.z) | ((unsigned)f2bf(a.w) << 16);
    o.z = (unsigned)f2bf(b.x) | ((unsigned)f2bf(b.y) << 16);
    o.w = (unsigned)f2bf(b.z) | ((unsigned)f2bf(b.w) << 16);
    *(uint4*)(ws + OFF_TBF + (size_t)m * (PPX * 2) + (size_t)kc * 16) = o;

    #pragma unroll
    for (int mk = 32; mk; mk >>= 1) part += __shfl_xor(part, mk);
    __shared__ float wsum[4];
    if ((threadIdx.x & 63) == 0) wsum[threadIdx.x >> 6] = part;
    __syncthreads();
    if (threadIdx.x == 0) {
        float tot = wsum[0] + wsum[1] + wsum[2] + wsum[3];
        atomicAdd((float*)(ws + OFF_TSUM) + m, tot);
    }
}

// ---------------------------------------------------------------------------
// Kernel 2: row softmax of pred_logits -> prob[800][81]
// ---------------------------------------------------------------------------
__global__ __launch_bounds__(64) void softmax_kernel(const float* __restrict__ logits,
                                                     float* __restrict__ prob) {
    int n = blockIdx.x;
    int l = threadIdx.x;
    const float* row = logits + n * NCLS;
    float v0 = row[l];
    float v1 = (l + 64 < NCLS) ? row[l + 64] : -INFINITY;
    float mx = fmaxf(v0, v1);
    #pragma unroll
    for (int mk = 32; mk; mk >>= 1) mx = fmaxf(mx, __shfl_xor(mx, mk));
    float e0 = __expf(v0 - mx);
    float e1 = (l + 64 < NCLS) ? __expf(v1 - mx) : 0.f;
    float s = e0 + e1;
    #pragma unroll
    for (int mk = 32; mk; mk >>= 1) s += __shfl_xor(s, mk);
    float inv = 1.f / s;
    prob[n * NCLS + l] = e0 * inv;
    if (l + 64 < NCLS) prob[n * NCLS + l + 64] = e1 * inv;
}

// ---------------------------------------------------------------------------
// Kernel 3: BARRIER-FREE wave-independent fused elementwise + dual GEMM.
// One wave (64-thr block) owns 16 rows x 160 cols x 1024-px chunk. No LDS.
// x: depth-2 register ping-pong (XA/XB). t: register fragments tf[2][10],
// reloaded from L2 right after their MFMA use (next half's ew hides latency).
// Elementwise computed exactly once per row (no duplication). MLP stays
// continuous per wave -- no collective barrier drains.
// ---------------------------------------------------------------------------
struct XS { float4 a, b, c, d; };   // kk0 px j..j+8 (a,b), kk1 px 32+j..+8 (c,d)

__device__ __forceinline__ void loadx(XS& x, const float* xrow, int it) {
    const float* p = xrow + it * BK;
    x.a = *(const float4*)(p);
    x.b = *(const float4*)(p + 4);
    x.c = *(const float4*)(p + 32);
    x.d = *(const float4*)(p + 36);
}

// 8 px: e^v via exp2, sigmoid = t2/(1+t2), softplus accumulated in log2 units.
__device__ __forceinline__ void ew8(const float4& u, const float4& v,
                                    bf16x8& xv, bf16x8& sv,
                                    float& slog2, float& sg_acc) {
    float vals[8] = {u.x, u.y, u.z, u.w, v.x, v.y, v.z, v.w};
    #pragma unroll
    for (int j = 0; j < 8; ++j) {
        float t = vals[j];
        float vl = fminf(t * 1.44269504089f, 126.f);         // overflow clamp
        float t2 = __builtin_amdgcn_exp2f(vl);               // e^t
        float d = 1.f + t2;
        float r = __builtin_amdgcn_rcpf(d);
        float sg = t2 * r;                                   // sigmoid(t)
        slog2 += __builtin_amdgcn_logf(d);                   // log2(1+e^t)
        sg_acc += sg;
        xv[j] = (short)f2bf(t);
        sv[j] = (short)f2bf(sg);
    }
}

__global__ __launch_bounds__(64, 2) void main_kernel(const float* __restrict__ pred_masks,
                                                     char* __restrict__ ws) {
    const int l = threadIdx.x;
    const int rt = blockIdx.x >> 6;      // row-tile 0..49
    const int s = blockIdx.x & 63;       // bid%8 = s%8 -> same-s waves share XCD L2
    const int k_base = s * CHUNK;
    const int lrow = l & 15;
    const int lseg = l >> 4;             // 0..3

    const float* xrow = pred_masks + (size_t)(rt * WROWS + lrow) * PPX + k_base + lseg * 8;
    const unsigned short* trow = (const unsigned short*)(ws + OFF_TBF)
                               + (size_t)lrow * PPX + k_base + lseg * 8;

    f32x4 accX[10], accS[10];
    #pragma unroll
    for (int c = 0; c < 10; ++c) { accX[c] = (f32x4)(0.f); accS[c] = (f32x4)(0.f); }
    float slog2 = 0.f, rs_sg = 0.f;

    bf16x8 tf0[10], tf1[10];             // t fragments, kk=0 / kk=1
    XS XA, XB;

    // prologue: t tile 0; x tiles 0,1
    #pragma unroll
    for (int c = 0; c < 10; ++c) {
        const unsigned short* tp = trow + (size_t)c * (16 * PPX);
        tf0[c] = *(const bf16x8*)(tp);
        tf1[c] = *(const bf16x8*)(tp + 32);
    }
    loadx(XA, xrow, 0);
    loadx(XB, xrow, 1);

    #pragma unroll 1
    for (int it = 0; it < ITERS; it += 2) {
        // ---------------- half A: tile it, consume XA + tf ----------------
        {
            bf16x8 ax0, as0, ax1, as1;
            ew8(XA.a, XA.b, ax0, as0, slog2, rs_sg);
            ew8(XA.c, XA.d, ax1, as1, slog2, rs_sg);
            int tr = it + 2; if (tr >= ITERS) tr = ITERS - 1;
            loadx(XA, xrow, tr);         // refill 2 tiles ahead

            #pragma unroll
            for (int c = 0; c < 10; ++c) {
                accX[c] = __builtin_amdgcn_mfma_f32_16x16x32_bf16(ax0, tf0[c], accX[c], 0, 0, 0);
                accS[c] = __builtin_amdgcn_mfma_f32_16x16x32_bf16(as0, tf0[c], accS[c], 0, 0, 0);
                accX[c] = __builtin_amdgcn_mfma_f32_16x16x32_bf16(ax1, tf1[c], accX[c], 0, 0, 0);
                accS[c] = __builtin_amdgcn_mfma_f32_16x16x32_bf16(as1, tf1[c], accS[c], 0, 0, 0);
            }
            // pin: reload tf only AFTER its MFMA use (avoid reg double-buffer)
            __builtin_amdgcn_sched_barrier(0);
            const int tn = it + 1;       // <= 15 always
            #pragma unroll
            for (int c = 0; c < 10; ++c) {
                const unsigned short* tp = trow + (size_t)c * (16 * PPX) + (size_t)tn * BK;
                tf0[c] = *(const bf16x8*)(tp);
                tf1[c] = *(const bf16x8*)(tp + 32);
            }
        }
        // ---------------- half B: tile it+1, consume XB + tf --------------
        {
            bf16x8 ax0, as0, ax1, as1;
            ew8(XB.a, XB.b, ax0, as0, slog2, rs_sg);
            ew8(XB.c, XB.d, ax1, as1, slog2, rs_sg);
            int tr = it + 3; if (tr >= ITERS) tr = ITERS - 1;
            loadx(XB, xrow, tr);

            #pragma unroll
            for (int c = 0; c < 10; ++c) {
                accX[c] = __builtin_amdgcn_mfma_f32_16x16x32_bf16(ax0, tf0[c], accX[c], 0, 0, 0);
                accS[c] = __builtin_amdgcn_mfma_f32_16x16x32_bf16(as0, tf0[c], accS[c], 0, 0, 0);
                accX[c] = __builtin_amdgcn_mfma_f32_16x16x32_bf16(ax1, tf1[c], accX[c], 0, 0, 0);
                accS[c] = __builtin_amdgcn_mfma_f32_16x16x32_bf16(as1, tf1[c], accS[c], 0, 0, 0);
            }
            __builtin_amdgcn_sched_barrier(0);
            int tn = it + 2; if (tn >= ITERS) tn = ITERS - 1;
            #pragma unroll
            for (int c = 0; c < 10; ++c) {
                const unsigned short* tp = trow + (size_t)c * (16 * PPX) + (size_t)tn * BK;
                tf0[c] = *(const bf16x8*)(tp);
                tf1[c] = *(const bf16x8*)(tp + 32);
            }
        }
    }

    asm volatile("s_waitcnt vmcnt(0)" ::: "memory");

    // ---- row sums: lanes l, l^16, l^32, l^48 share a row
    float rs_sp = slog2 * 0.69314718056f;
    rs_sp += __shfl_xor(rs_sp, 16); rs_sp += __shfl_xor(rs_sp, 32);
    rs_sg += __shfl_xor(rs_sg, 16); rs_sg += __shfl_xor(rs_sg, 32);
    float* acc_row = (float*)(ws + OFF_ROW);
    float* acc_ssum = (float*)(ws + OFF_SSUM);
    if (l < 16) {
        int n = rt * WROWS + l;
        atomicAdd(acc_row + n, rs_sp);
        atomicAdd(acc_ssum + n, rs_sg);
    }

    // ---- split-K accumulate the C fragments
    float* acc_cross = (float*)(ws + OFF_CROSS);
    float* acc_sdot = (float*)(ws + OFF_SDOT);
    #pragma unroll
    for (int c = 0; c < 10; ++c) {
        int mcol = c * 16 + lrow;
        #pragma unroll
        for (int i = 0; i < 4; ++i) {
            int nrow = rt * WROWS + lseg * 4 + i;
            atomicAdd(acc_cross + nrow * MT + mcol, accX[c][i]);
            atomicAdd(acc_sdot + nrow * MT + mcol, accS[c][i]);
        }
    }
}

// ---------------------------------------------------------------------------
// Kernel 4: combine into C[n][m]
// ---------------------------------------------------------------------------
__global__ __launch_bounds__(256) void final_kernel(const int* __restrict__ tgt_ids,
                                                    const char* __restrict__ ws,
                                                    float* __restrict__ out) {
    int idx = blockIdx.x * 256 + threadIdx.x;   // 0..127999
    int n = idx / MT;
    int m = idx - n * MT;
    const float* prob = (const float*)(ws + OFF_PROB);
    const float* acc_cross = (const float*)(ws + OFF_CROSS);
    const float* acc_sdot = (const float*)(ws + OFF_SDOT);
    const float* acc_row = (const float*)(ws + OFF_ROW);
    const float* acc_ssum = (const float*)(ws + OFF_SSUM);
    const float* tsum = (const float*)(ws + OFF_TSUM);

    float cls = -prob[n * NCLS + tgt_ids[m]];
    float cmask = (acc_row[n] - acc_cross[idx]) * (1.f / PPX);
    float cdice = 1.f - (2.f * acc_sdot[idx] + 1.f) / (acc_ssum[n] + tsum[m] + 1.f);
    out[idx] = cls + cmask + cdice;
}

extern "C" void kernel_launch(void* const* d_in, const int* in_sizes, int n_in,
                              void* d_out, int out_size, void* d_ws, size_t ws_size,
                              hipStream_t stream) {
    const float* pred_logits = (const float*)d_in[0];
    const float* pred_masks  = (const float*)d_in[1];
    const int*   tgt_ids     = (const int*)d_in[2];
    const float* tgt_mask    = (const float*)d_in[3];
    char* ws = (char*)d_ws;

    (void)hipMemsetAsync(ws + OFF_CROSS, 0, OFF_END - OFF_CROSS, stream);
    prep_kernel<<<5120, 256, 0, stream>>>(tgt_mask, ws);
    softmax_kernel<<<NROWS, 64, 0, stream>>>(pred_logits, (float*)(ws + OFF_PROB));
    main_kernel<<<RB * SSPLIT, 64, 0, stream>>>(pred_masks, ws);
    final_kernel<<<500, 256, 0, stream>>>(tgt_ids, ws, (float*)d_out);
}